// Round 6
// baseline (731.670 us; speedup 1.0000x reference)
//
#include <hip/hip_runtime.h>
#include <cstddef>

typedef _Float16 f16;
typedef f16 f16x4 __attribute__((ext_vector_type(4)));
typedef f16 f16x8 __attribute__((ext_vector_type(8)));
typedef float f32x4 __attribute__((ext_vector_type(4)));

// async global->LDS, 16B per lane. LDS dest = uniform base + lane*16 (HW);
// global src is per-lane.
__device__ inline void gld_lds16(const f16* g, f16* l) {
    __builtin_amdgcn_global_load_lds(
        (const __attribute__((address_space(1))) void*)g,
        (__attribute__((address_space(3))) void*)l, 16, 0, 0);
}

// ---------------------------------------------------------------------------
// MFMA submanifold conv, A-direct / B-in-LDS (structure validated R5).
//  - wave owns 16 sites; A fragment = per-lane 16B loads from pre-split f16
//    planes (hi at base, lo at +in_plane). Row N of input = zeros; missing
//    neighbors and tail sites map there -> branch-free.
//  - B fragments staged per-k into LDS dbuf via global_load_lds; ONE barrier
//    per k, stage issued at phase start so drain hides under MFMA phase.
//  - TERMS=2: Markidis f16 split (hi + lo*2^12), 3 MFMAs/pair (~fp32 accuracy
//    for the mask-threshold chain). TERMS=1: plain f16 (points chain).
//  - WAVES=16 (1024 thr): 2 blocks/CU x 16 waves = 32 waves/CU (R5 was 61%).
// ---------------------------------------------------------------------------
template<int C, int NTB, int CS, int TERMS, int WAVES, int BMODE, int OUTM>
__global__ __launch_bounds__(WAVES * 64)
void conv_mfma(const f16* __restrict__ fin, size_t in_plane,
               const int* __restrict__ nbr,
               const f16* __restrict__ Wb,
               void* __restrict__ outv, int ostride, int ooff, size_t out_plane,
               int CO_real, int N, int Nstore, int tilesPad)
{
    constexpr int KK   = C / 32;
    constexpr int CH   = KK * NTB * TERMS;      // 1KB fragments per (k, cs)
    constexpr int ROWS = WAVES * 16;
    constexpr int BUFS = (BMODE == 0) ? 27 : 2;
    __shared__ f16 sB[BUFS * CH * 512];

    const int tid  = threadIdx.x;
    const int lane = tid & 63;
    const int w    = tid >> 6;
    const int tile = blockIdx.x % tilesPad;
    const int cs   = blockIdx.x / tilesPad;
    const int n0   = tile * ROWS;
    const int site = n0 + w * 16 + (lane & 15);
    const bool sv  = site < N;
    const int NZ   = N;                          // zero row
    const int h8   = (lane >> 4) * 8;

    auto stageK = [&](int k, int buf) {
        const f16* src = Wb + ((size_t)(k * CS + cs) * CH) * 512 + lane * 8;
        f16* dst = &sB[(size_t)buf * CH * 512];
        for (int c = w; c < CH; c += WAVES)
            gld_lds16(src + (size_t)c * 512, dst + (size_t)c * 512);
    };

    f32x4 acc[NTB];
    f32x4 acc2[NTB];
#pragma unroll
    for (int nt = 0; nt < NTB; ++nt) {
        acc[nt]  = (f32x4){0.f, 0.f, 0.f, 0.f};
        acc2[nt] = (f32x4){0.f, 0.f, 0.f, 0.f};
    }

    if constexpr (BMODE == 0) {
        for (int c = w; c < 27 * CH; c += WAVES)
            gld_lds16(Wb + (size_t)c * 512 + lane * 8, &sB[(size_t)c * 512]);
    } else {
        stageK(0, 0);
    }

    int idxC;
    { int r = sv ? nbr[(size_t)site * 27] : -1; idxC = (r < 0) ? NZ : r; }
    __syncthreads();   // B(0) (or all B) staged

    int cur = 0;
    for (int k = 0; k < 27; ++k) {
        if (BMODE == 1 && k + 1 < 27) stageK(k + 1, cur ^ 1);

        // A fragments for this k (per-lane direct gather)
        const f16* arow = fin + (size_t)idxC * C + h8;
        f16x8 va[KK], vl[KK];
#pragma unroll
        for (int kk = 0; kk < KK; ++kk) {
            va[kk] = *(const f16x8*)(arow + kk * 32);
            if constexpr (TERMS == 2)
                vl[kk] = *(const f16x8*)(arow + in_plane + kk * 32);
        }
        // prefetch next k's neighbor index
        int idxN = NZ;
        if (k + 1 < 27) {
            int r = sv ? nbr[(size_t)site * 27 + k + 1] : -1;
            idxN = (r < 0) ? NZ : r;
        }

        const f16* sBc = &sB[(size_t)((BMODE == 0) ? k : cur) * CH * 512] + lane * 8;
#pragma unroll
        for (int kk = 0; kk < KK; ++kk) {
#pragma unroll
            for (int nt = 0; nt < NTB; ++nt) {
                const f16* bp = sBc + (size_t)((kk * NTB + nt) * TERMS) * 512;
                const f16x8 bh = *(const f16x8*)bp;
                acc[nt] = __builtin_amdgcn_mfma_f32_16x16x32_f16(va[kk], bh, acc[nt], 0, 0, 0);
                if constexpr (TERMS == 2) {
                    const f16x8 bl = *(const f16x8*)(bp + 512);
                    acc2[nt] = __builtin_amdgcn_mfma_f32_16x16x32_f16(va[kk], bl, acc2[nt], 0, 0, 0);
                    acc2[nt] = __builtin_amdgcn_mfma_f32_16x16x32_f16(vl[kk], bh, acc2[nt], 0, 0, 0);
                }
            }
        }
        idxC = idxN;
        if constexpr (BMODE == 1) { __syncthreads(); cur ^= 1; }
    }

    // epilogue: D col=lane&15, row=(lane>>4)*4+j
    const int colg = lane & 15;
    const int rg   = lane >> 4;
#pragma unroll
    for (int nt = 0; nt < NTB; ++nt) {
#pragma unroll
        for (int j = 0; j < 4; ++j) {
            float r = acc[nt][j];
            if constexpr (TERMS == 2) r += acc2[nt][j] * (1.f / 4096.f);
            const int n  = n0 + w * 16 + rg * 4 + j;
            const int co = (cs * NTB + nt) * 16 + colg;
            if (n < Nstore && co < CO_real) {
                if constexpr (OUTM == 0) {
                    ((float*)outv)[(size_t)n * ostride + ooff + co] = r;
                } else if constexpr (OUTM == 1) {
                    ((f16*)outv)[(size_t)n * ostride + co] = (f16)r;
                } else {
                    f16* o = (f16*)outv;
                    const f16 h = (f16)r;
                    o[(size_t)n * ostride + co] = h;
                    o[out_plane + (size_t)n * ostride + co] = (f16)((r - (float)h) * 4096.f);
                }
            }
        }
    }
}

// ---------------------------------------------------------------------------
// P-factorized score: P[k][R][c] = f[R] @ Ws[k][:,c]  computed as ONE dense
// GEMM  f[N x C] @ Wflat[C x 54->64]  (no gather; A rows = own sites).
// Split f16 input planes, 3-MFMA split accuracy. P is f32 [27][N][2].
// ---------------------------------------------------------------------------
template<int C>
__global__ __launch_bounds__(256)
void pgemm_score(const f16* __restrict__ fin, size_t plane,
                 const f16* __restrict__ Wb,   // (C/32)*4*2 chunks
                 float* __restrict__ P, int N)
{
    constexpr int KK = C / 32;
    constexpr int CH = KK * 4 * 2;
    __shared__ f16 sB[CH * 512];

    const int tid  = threadIdx.x;
    const int lane = tid & 63;
    const int w    = tid >> 6;

    for (int c = w; c < CH; c += 4)
        gld_lds16(Wb + (size_t)c * 512 + lane * 8, &sB[(size_t)c * 512]);

    const int n0 = blockIdx.x * 64;
    int site = n0 + w * 16 + (lane & 15);
    if (site > N) site = N;                 // zero row for tails
    const int h8 = (lane >> 4) * 8;

    f16x8 va[KK], vl[KK];
    const f16* arow = fin + (size_t)site * C + h8;
#pragma unroll
    for (int kk = 0; kk < KK; ++kk) {
        va[kk] = *(const f16x8*)(arow + kk * 32);
        vl[kk] = *(const f16x8*)(arow + plane + kk * 32);
    }

    f32x4 acc[4], acc2[4];
#pragma unroll
    for (int nt = 0; nt < 4; ++nt) {
        acc[nt]  = (f32x4){0.f, 0.f, 0.f, 0.f};
        acc2[nt] = (f32x4){0.f, 0.f, 0.f, 0.f};
    }
    __syncthreads();

#pragma unroll
    for (int kk = 0; kk < KK; ++kk) {
#pragma unroll
        for (int nt = 0; nt < 4; ++nt) {
            const f16* bp = &sB[(size_t)((kk * 4 + nt) * 2) * 512] + lane * 8;
            const f16x8 bh = *(const f16x8*)bp;
            const f16x8 bl = *(const f16x8*)(bp + 512);
            acc[nt]  = __builtin_amdgcn_mfma_f32_16x16x32_f16(va[kk], bh, acc[nt], 0, 0, 0);
            acc2[nt] = __builtin_amdgcn_mfma_f32_16x16x32_f16(va[kk], bl, acc2[nt], 0, 0, 0);
            acc2[nt] = __builtin_amdgcn_mfma_f32_16x16x32_f16(vl[kk], bh, acc2[nt], 0, 0, 0);
        }
    }

    const int colg = lane & 15;
    const int rg   = lane >> 4;
#pragma unroll
    for (int nt = 0; nt < 4; ++nt) {
#pragma unroll
        for (int j = 0; j < 4; ++j) {
            const float r = acc[nt][j] + acc2[nt][j] * (1.f / 4096.f);
            const int n  = n0 + w * 16 + rg * 4 + j;
            const int co = nt * 16 + colg;
            if (n < N && co < 54)
                P[(size_t)(co >> 1) * N * 2 + (size_t)n * 2 + (co & 1)] = r;
        }
    }
}

// score(S) = sum_k P[k][nbr(S,k)]  (f32, k-ordered like the reference);
// also fills the coords columns of ppn.
__global__ __launch_bounds__(256)
void reduce_score(const float* __restrict__ P, const int* __restrict__ nbr,
                  const int* __restrict__ coords, float* __restrict__ ppn, int N)
{
    const int site = blockIdx.x * 256 + threadIdx.x;
    if (site >= N) return;
    float s0 = 0.f, s1 = 0.f;
    const size_t pl = (size_t)N * 2;
#pragma unroll
    for (int k = 0; k < 27; ++k) {
        const int idx = nbr[(size_t)site * 27 + k];
        if (idx >= 0) {
            const float2 p = *(const float2*)(P + (size_t)k * pl + (size_t)idx * 2);
            s0 += p.x; s1 += p.y;
        }
    }
    float* row = ppn + (size_t)site * 6;
    const int* cr = coords + (size_t)site * 4;
    row[0] = (float)cr[0]; row[1] = (float)cr[1];
    row[2] = (float)cr[2]; row[3] = (float)cr[3];
    row[4] = s0; row[5] = s1;
}

// ---------------------------------------------------------------------------
// Pre-pass: f32 rows (optionally x att-mask) -> f16 split planes, plus a
// zero row at index N (gather target for missing neighbors / tail sites).
// ---------------------------------------------------------------------------
template<int TERMS>
__global__ __launch_bounds__(256)
void prepass(const float* __restrict__ f, const float* __restrict__ att,
             f16* __restrict__ dst, size_t plane, int C4, int N)
{
    const size_t i = (size_t)blockIdx.x * 256 + threadIdx.x;
    const size_t total = (size_t)(N + 1) * C4;
    if (i >= total) return;
    const int row = (int)(i / C4);
    float4 v = make_float4(0.f, 0.f, 0.f, 0.f);
    if (row < N) {
        v = *(const float4*)(f + i * 4);
        if (att != nullptr) {
            const float a = att[row];
            v.x *= a; v.y *= a; v.z *= a; v.w *= a;
        }
    }
    const float xs[4] = {v.x, v.y, v.z, v.w};
    f16x4 hi, lo;
#pragma unroll
    for (int j = 0; j < 4; ++j) {
        const f16 h = (f16)xs[j];
        hi[j] = h;
        lo[j] = (f16)((xs[j] - (float)h) * 4096.f);
    }
    *(f16x4*)(dst + i * 4) = hi;
    if constexpr (TERMS == 2)
        *(f16x4*)(dst + plane + i * 4) = lo;
}

// Pack fp32 W[27][C][CO_real] into fragment chunks:
// chunk id = ((((k*CS + cs)*KK + kk)*NTB + nt)*TERMS + term), 512 f16 each.
__global__ __launch_bounds__(256)
void pack_w_f16(const float* __restrict__ W, f16* __restrict__ Wb,
                int C, int CO_real, int CS, int NTB, int TERMS)
{
    const int KK = C / 32;
    const int total = 27 * CS * KK * NTB * TERMS * 64;
    const int t = blockIdx.x * blockDim.x + threadIdx.x;
    if (t >= total) return;
    const int lane = t & 63;
    int cid = t >> 6;
    const int term = cid % TERMS; cid /= TERMS;
    const int nt   = cid % NTB;   cid /= NTB;
    const int kk   = cid % KK;    cid /= KK;
    const int cs   = cid % CS;
    const int k    = cid / CS;
    const int co   = (cs * NTB + nt) * 16 + (lane & 15);
#pragma unroll
    for (int j = 0; j < 8; ++j) {
        const int ci = kk * 32 + (lane >> 4) * 8 + j;
        const float x = (co < CO_real) ? W[((size_t)k * C + ci) * CO_real + co] : 0.f;
        const f16 h = (f16)x;
        Wb[(size_t)t * 8 + j] = (term == 0) ? h : (f16)((x - (float)h) * 4096.f);
    }
}

// Pack score weights [27][C][2] as a flat [C x 54->64] fragment set,
// chunk id = ((kk*4 + nt)*2 + term); flat col co = 2k + c.
__global__ __launch_bounds__(256)
void pack_ws_flat(const float* __restrict__ W, f16* __restrict__ Wb, int C)
{
    const int KK = C / 32;
    const int total = KK * 4 * 2 * 64;
    const int t = blockIdx.x * blockDim.x + threadIdx.x;
    if (t >= total) return;
    const int lane = t & 63;
    int cid = t >> 6;
    const int term = cid % 2;
    const int nt   = (cid >> 1) % 4;
    const int kk   = cid >> 3;
    const int co   = nt * 16 + (lane & 15);
#pragma unroll
    for (int j = 0; j < 8; ++j) {
        const int ci = kk * 32 + (lane >> 4) * 8 + j;
        const float x = (co < 54) ? W[((size_t)(co >> 1) * C + ci) * 2 + (co & 1)] : 0.f;
        const f16 h = (f16)x;
        Wb[(size_t)t * 8 + j] = (term == 0) ? h : (f16)((x - (float)h) * 4096.f);
    }
}

// Pack the fused head [27][32][{3|2|5}->10] directly into fragment chunks
// (chunk per k; single term).
__global__ __launch_bounds__(256)
void pack_wh_frag(const float* __restrict__ wp, const float* __restrict__ ws,
                  const float* __restrict__ wt, f16* __restrict__ Wb)
{
    const int t = blockIdx.x * blockDim.x + threadIdx.x;
    if (t >= 27 * 64) return;
    const int lane = t & 63;
    const int k    = t >> 6;
    const int co   = lane & 15;
#pragma unroll
    for (int j = 0; j < 8; ++j) {
        const int ci = (lane >> 4) * 8 + j;
        float x = 0.f;
        if (co < 3)       x = wp[((size_t)k * 32 + ci) * 3 + co];
        else if (co < 5)  x = ws[((size_t)k * 32 + ci) * 2 + (co - 3)];
        else if (co < 10) x = wt[((size_t)k * 32 + ci) * 5 + (co - 5)];
        Wb[(size_t)t * 8 + j] = (f16)x;
    }
}

__global__ __launch_bounds__(256)
void att_kernel(const float* __restrict__ ppn, const int* __restrict__ parent,
                float* __restrict__ att, int N)
{
    const int i = blockIdx.x * blockDim.x + threadIdx.x;
    if (i >= N) return;
    const int p = parent[i];
    const float s0 = ppn[(size_t)p * 6 + 4];
    const float s1 = ppn[(size_t)p * 6 + 5];
    const float m  = fmaxf(s0, s1);
    const float e0 = expf(s0 - m);
    const float e1 = expf(s1 - m);
    const float p1 = e1 / (e0 + e1);
    att[i] = (p1 > 0.8f) ? 1.f : 0.f;
}

extern "C" void kernel_launch(void* const* d_in, const int* in_sizes, int n_in,
                              void* d_out, int out_size, void* d_ws, size_t ws_size,
                              hipStream_t stream)
{
    const float* f1       = (const float*)d_in[0];
    const float* f2       = (const float*)d_in[1];
    const float* f3       = (const float*)d_in[2];
    const float* w1_conv  = (const float*)d_in[3];
    const float* w1_score = (const float*)d_in[4];
    const float* w2_conv  = (const float*)d_in[5];
    const float* w2_score = (const float*)d_in[6];
    const float* w3_conv  = (const float*)d_in[7];
    const float* w3_pix   = (const float*)d_in[8];
    const float* w3_score = (const float*)d_in[9];
    const float* w3_type  = (const float*)d_in[10];
    const int* coords1    = (const int*)d_in[11];
    const int* coords2    = (const int*)d_in[12];
    const int* nbr1       = (const int*)d_in[13];
    const int* nbr2       = (const int*)d_in[14];
    const int* nbr3       = (const int*)d_in[15];
    const int* parent12   = (const int*)d_in[16];
    const int* parent23   = (const int*)d_in[17];

    const int N1 = in_sizes[0] / 160;   // 20000
    const int N2 = in_sizes[1] / 96;    // 160000
    const int N3 = in_sizes[2] / 32;    // 320000

    // Output layout: points[N3,10] | ppn1[N1,6] | ppn2[N2,6] | att[N2] | att2[N3]
    float* points = (float*)d_out;
    float* ppn1   = points + (size_t)N3 * 10;
    float* ppn2   = ppn1 + (size_t)N1 * 6;
    float* attn   = ppn2 + (size_t)N2 * 6;
    float* attn2  = attn + (size_t)N2;

    // Workspace (all conv inputs have N+1 rows; row N = zeros).
    // Region reuse by lifetime:
    //   f1s region: f1 split (conv1) -> P1 (pgemm1/reduce1) -> f3s (level 3)
    //   f2s region: f2 split (conv2) -> P2 (pgemm2/reduce2) -> zs (conv3/head)
    const size_t p1 = (size_t)(N1 + 1) * 160;
    const size_t p2 = (size_t)(N2 + 1) * 96;
    f16* f1s  = (f16*)d_ws;           // 2*p1
    f16* xs   = f1s + 2 * p1;         // 2*p1
    f16* f2s  = xs + 2 * p1;          // 2*p2
    f16* ys   = f2s + 2 * p2;         // 2*p2
    float* P1 = (float*)f1s;          // 27*N1*2 f32 (4.3MB <= 12.8MB)
    f16* f3s  = f1s;                  // (N3+1)*32 f16 (20.5MB <= 25.6MB w/ xs)
    float* P2 = (float*)f2s;          // 27*N2*2 f32 (34.6MB <= 61.4MB)
    f16* zs   = f2s;                  // (N3+1)*32 f16 (after P2 dead)
    f16* Wb1  = ys + 2 * p2;          // 2700 chunks
    f16* Wb2  = Wb1 + (size_t)2700 * 512;   // 972
    f16* Wb3  = Wb2 + (size_t)972 * 512;    // 54
    f16* Wbh  = Wb3 + (size_t)54 * 512;     // 27
    f16* Wsf1 = Wbh + (size_t)27 * 512;     // 40 (score1 flat)
    f16* Wsf2 = Wsf1 + (size_t)40 * 512;    // 24 (score2 flat)

    // ---- weight packing ----
    pack_w_f16<<<(2700 * 64 + 255) / 256, 256, 0, stream>>>(w1_conv, Wb1, 160, 160, 5, 2, 2);
    pack_w_f16<<<(972 * 64 + 255) / 256, 256, 0, stream>>>(w2_conv, Wb2, 96, 96, 2, 3, 2);
    pack_w_f16<<<(54 * 64 + 255) / 256, 256, 0, stream>>>(w3_conv, Wb3, 32, 32, 1, 2, 1);
    pack_wh_frag<<<(27 * 64 + 255) / 256, 256, 0, stream>>>(w3_pix, w3_score, w3_type, Wbh);
    pack_ws_flat<<<(40 * 64 + 255) / 256, 256, 0, stream>>>(w1_score, Wsf1, 160);
    pack_ws_flat<<<(24 * 64 + 255) / 256, 256, 0, stream>>>(w2_score, Wsf2, 96);

    // ---- level 1 ----
    prepass<2><<<(int)(((size_t)(N1 + 1) * 40 + 255) / 256), 256, 0, stream>>>(
        f1, nullptr, f1s, p1, 40, N1);
    // conv1: C=160 NTB=2 CS=5 split, 16 waves, dbuf. tiles=79 -> pad 80.
    conv_mfma<160, 2, 5, 2, 16, 1, 2><<<80 * 5, 1024, 0, stream>>>(
        f1s, p1, nbr1, Wb1, xs, 160, 0, p1, 160, N1, N1 + 1, 80);
    pgemm_score<160><<<(N1 + 63) / 64, 256, 0, stream>>>(xs, p1, Wsf1, P1, N1);
    reduce_score<<<(N1 + 255) / 256, 256, 0, stream>>>(P1, nbr1, coords1, ppn1, N1);
    att_kernel<<<(N2 + 255) / 256, 256, 0, stream>>>(ppn1, parent12, attn, N2);

    // ---- level 2 ----
    prepass<2><<<(int)(((size_t)(N2 + 1) * 24 + 255) / 256), 256, 0, stream>>>(
        f2, attn, f2s, p2, 24, N2);
    // conv2: C=96 NTB=3 CS=2 split, 16 waves, dbuf. tiles=626 -> pad 632.
    conv_mfma<96, 3, 2, 2, 16, 1, 2><<<632 * 2, 1024, 0, stream>>>(
        f2s, p2, nbr2, Wb2, ys, 96, 0, p2, 96, N2, N2 + 1, 632);
    pgemm_score<96><<<(N2 + 63) / 64, 256, 0, stream>>>(ys, p2, Wsf2, P2, N2);
    reduce_score<<<(N2 + 255) / 256, 256, 0, stream>>>(P2, nbr2, coords2, ppn2, N2);
    att_kernel<<<(N3 + 255) / 256, 256, 0, stream>>>(ppn2, parent23, attn2, N3);

    // ---- level 3 (points chain, single-term f16) ----
    prepass<1><<<(int)(((size_t)(N3 + 1) * 8 + 255) / 256), 256, 0, stream>>>(
        f3, attn2, f3s, 0, 8, N3);
    // conv3: C=32 NTB=2 whole-B (54KB), no k-loop barriers. tiles=1251.
    conv_mfma<32, 2, 1, 1, 16, 0, 1><<<1251, 1024, 0, stream>>>(
        f3s, 0, nbr3, Wb3, zs, 32, 0, 0, 32, N3, N3 + 1, 1251);
    // head: C=32 NTB=1 whole-B (27KB). tiles=1250.
    conv_mfma<32, 1, 1, 1, 16, 0, 0><<<1250, 1024, 0, stream>>>(
        zs, 0, nbr3, Wbh, points, 10, 0, 0, 10, N3, N3, 1250);
}

// Round 7
// 666.100 us; speedup vs baseline: 1.0984x; 1.0984x over previous
//
#include <hip/hip_runtime.h>
#include <cstddef>

typedef _Float16 f16;
typedef f16 f16x4 __attribute__((ext_vector_type(4)));
typedef f16 f16x8 __attribute__((ext_vector_type(8)));
typedef float f32x4 __attribute__((ext_vector_type(4)));

// async global->LDS, 16B per lane. LDS dest = uniform base + lane*16 (HW);
// global src is per-lane.
__device__ inline void gld_lds16(const f16* g, f16* l) {
    __builtin_amdgcn_global_load_lds(
        (const __attribute__((address_space(1))) void*)g,
        (__attribute__((address_space(3))) void*)l, 16, 0, 0);
}

// ---------------------------------------------------------------------------
// MFMA submanifold conv, A-direct / B-in-LDS.
//  - wave owns 16 sites; A fragment = per-lane 16B loads from pre-split f16
//    planes (hi at base, lo at +in_plane). Row N of input = zeros.
//  - B fragments staged per-k into LDS dbuf via global_load_lds, ONE barrier
//    per k. ORDER MATTERS: A-loads are issued BEFORE staging so the MFMA
//    phase waits only on A (vmcnt(N), staging stays in flight and drains at
//    the end-of-phase barrier, hidden under MFMA+ds_read). R5/R6 issued
//    staging first -> forced vmcnt(0) serialization (44% MfmaUtil).
//  - PIPEA=1: A registers double-buffered; A(k+1) issued at phase start,
//    MFMA(k) uses registers loaded BEFORE the previous barrier -> zero wait.
//  - TERMS=2: Markidis f16 split (hi + lo*2^12), 3 MFMAs/pair, ~fp32 accuracy
//    (mask-threshold chain). TERMS=1: plain f16 (points chain).
//  - Bijective XCD-chunk swizzle: requires tilesPad*CS % 8 == 0; cs-twins and
//    neighbor tiles share an XCD L2.
// ---------------------------------------------------------------------------
template<int C, int NTB, int CS, int TERMS, int WAVES, int BMODE, int OUTM, int PIPEA>
__global__ __launch_bounds__(WAVES * 64)
void conv_mfma(const f16* __restrict__ fin, size_t in_plane,
               const int* __restrict__ nbr,
               const f16* __restrict__ Wb,
               void* __restrict__ outv, int ostride, int ooff, size_t out_plane,
               int CO_real, int N, int Nstore, int tilesPad)
{
    constexpr int KK   = C / 32;
    constexpr int KKL  = (TERMS == 2) ? KK : 1;
    constexpr int CH   = KK * NTB * TERMS;      // 1KB fragment chunks per (k,cs)
    constexpr int ROWS = WAVES * 16;
    constexpr int BUFS = (BMODE == 0) ? 27 : 2;
    __shared__ f16 sB[BUFS * CH * 512];

    const int lane = threadIdx.x & 63;
    const int w    = threadIdx.x >> 6;
    int gid = blockIdx.x;
    { const int q = (tilesPad * CS) >> 3; gid = (gid & 7) * q + (gid >> 3); }
    const int tile = gid / CS;
    const int cs   = gid - tile * CS;
    const int n0   = tile * ROWS;
    const int site = n0 + w * 16 + (lane & 15);
    const bool sv  = site < N;
    const int NZ   = N;                          // zero row
    const int h8   = (lane >> 4) * 8;
    const int* nrow = nbr + (size_t)site * 27;   // only deref'd when sv

    auto stageK = [&](int k, int buf) {
        const f16* src = Wb + ((size_t)(k * CS + cs) * CH) * 512 + lane * 8;
        f16* dst = &sB[(size_t)buf * CH * 512];
#pragma unroll
        for (int c = w; c < CH; c += WAVES)
            gld_lds16(src + (size_t)c * 512, dst + (size_t)c * 512);
    };

    f32x4 acc[NTB], acc2[NTB];
#pragma unroll
    for (int nt = 0; nt < NTB; ++nt) {
        acc[nt]  = (f32x4){0.f, 0.f, 0.f, 0.f};
        acc2[nt] = (f32x4){0.f, 0.f, 0.f, 0.f};
    }

    f16x8 vaA[KK], vlA[KKL], vaB[KK], vlB[KKL];

    auto loadA = [&](int idx, f16x8* va, f16x8* vl) {
        const f16* arow = fin + (size_t)idx * C + h8;
#pragma unroll
        for (int kk = 0; kk < KK; ++kk) {
            va[kk] = *(const f16x8*)(arow + kk * 32);
            if constexpr (TERMS == 2)
                vl[kk] = *(const f16x8*)(arow + in_plane + kk * 32);
        }
    };

    auto mfmaPhase = [&](const f16x8* va, const f16x8* vl, int kbuf) {
        const f16* sBc = &sB[(size_t)kbuf * CH * 512] + lane * 8;
#pragma unroll
        for (int kk = 0; kk < KK; ++kk) {
#pragma unroll
            for (int nt = 0; nt < NTB; ++nt) {
                const f16* bp = sBc + (size_t)((kk * NTB + nt) * TERMS) * 512;
                const f16x8 bh = *(const f16x8*)bp;
                acc[nt] = __builtin_amdgcn_mfma_f32_16x16x32_f16(va[kk], bh, acc[nt], 0, 0, 0);
                if constexpr (TERMS == 2) {
                    const f16x8 bl = *(const f16x8*)(bp + 512);
                    acc2[nt] = __builtin_amdgcn_mfma_f32_16x16x32_f16(va[kk], bl, acc2[nt], 0, 0, 0);
                    acc2[nt] = __builtin_amdgcn_mfma_f32_16x16x32_f16(vl[kk], bh, acc2[nt], 0, 0, 0);
                }
            }
        }
    };

    // ---- prologue: A(0) + B(0) (or all B) in flight, then barrier ----
    int idxC;
    { int r = sv ? nrow[0] : -1; idxC = (r < 0) ? NZ : r; }
    loadA(idxC, vaA, vlA);                 // A first (see ordering note)
    if constexpr (BMODE == 0) {
#pragma unroll
        for (int c = w; c < 27 * CH; c += WAVES)
            gld_lds16(Wb + (size_t)c * 512 + lane * 8, &sB[(size_t)c * 512]);
    } else {
        stageK(0, 0);
    }
    int idxN;
    { int r = sv ? nrow[1] : -1; idxN = (r < 0) ? NZ : r; }
    __syncthreads();                       // drains A(0) + B staging

    if constexpr (PIPEA) {
        auto body = [&](int k, f16x8* vac, f16x8* vlc, f16x8* van, f16x8* vln) {
            if (k >= 27) return;
            if (k + 1 < 27) {
                loadA(idxN, van, vln);                     // A(k+1) in flight
                int r = (k + 2 < 27 && sv) ? nrow[k + 2] : -1;
                idxN = (r < 0) ? NZ : r;
                if constexpr (BMODE == 1) stageK(k + 1, (k + 1) & 1);
            }
            mfmaPhase(vac, vlc, (BMODE == 0) ? k : (k & 1)); // A(k) already done
            if (BMODE == 1 && k + 1 < 27) __syncthreads();   // drains A+staging
        };
        for (int k2 = 0; k2 < 27; k2 += 2) {
            body(k2, vaA, vlA, vaB, vlB);
            body(k2 + 1, vaB, vlB, vaA, vlA);
        }
    } else {
        for (int k = 0; k < 27; ++k) {
            if (BMODE == 1 && k + 1 < 27) stageK(k + 1, (k + 1) & 1);
            mfmaPhase(vaA, vlA, (BMODE == 0) ? k : (k & 1));
            if (BMODE == 1 && k + 1 < 27) __syncthreads();
            if (k + 1 < 27) {
                loadA(idxN, vaA, vlA);
                int r = (k + 2 < 27 && sv) ? nrow[k + 2] : -1;
                idxN = (r < 0) ? NZ : r;
            }
        }
    }

    // ---- epilogue: D col=lane&15, row=(lane>>4)*4+j ----
    const int colg = lane & 15;
    const int rg   = lane >> 4;
#pragma unroll
    for (int nt = 0; nt < NTB; ++nt) {
#pragma unroll
        for (int j = 0; j < 4; ++j) {
            float r = acc[nt][j];
            if constexpr (TERMS == 2) r += acc2[nt][j] * (1.f / 4096.f);
            const int n  = n0 + w * 16 + rg * 4 + j;
            const int co = (cs * NTB + nt) * 16 + colg;
            if (n < Nstore && co < CO_real) {
                if constexpr (OUTM == 0) {
                    ((float*)outv)[(size_t)n * ostride + ooff + co] = r;
                } else if constexpr (OUTM == 1) {
                    ((f16*)outv)[(size_t)n * ostride + co] = (f16)r;
                } else {
                    f16* o = (f16*)outv;
                    const f16 h = (f16)r;
                    o[(size_t)n * ostride + co] = h;
                    o[out_plane + (size_t)n * ostride + co] = (f16)((r - (float)h) * 4096.f);
                }
            }
        }
    }
}

// ---------------------------------------------------------------------------
// P-factorized score: P[k][R][c] = f[R] @ Ws[k][:,c]  computed as ONE dense
// GEMM  f[N x C] @ Wflat[C x 54->64]  (no gather; A rows = own sites).
// Split f16 input planes, 3-MFMA split accuracy. P is f32 [27][N][2].
// ---------------------------------------------------------------------------
template<int C>
__global__ __launch_bounds__(256)
void pgemm_score(const f16* __restrict__ fin, size_t plane,
                 const f16* __restrict__ Wb,   // (C/32)*4*2 chunks
                 float* __restrict__ P, int N)
{
    constexpr int KK = C / 32;
    constexpr int CH = KK * 4 * 2;
    __shared__ f16 sB[CH * 512];

    const int tid  = threadIdx.x;
    const int lane = tid & 63;
    const int w    = tid >> 6;

    const int n0 = blockIdx.x * 64;
    int site = n0 + w * 16 + (lane & 15);
    if (site > N) site = N;                 // zero row for tails
    const int h8 = (lane >> 4) * 8;

    f16x8 va[KK], vl[KK];
    const f16* arow = fin + (size_t)site * C + h8;
#pragma unroll
    for (int kk = 0; kk < KK; ++kk) {
        va[kk] = *(const f16x8*)(arow + kk * 32);
        vl[kk] = *(const f16x8*)(arow + plane + kk * 32);
    }
    for (int c = w; c < CH; c += 4)
        gld_lds16(Wb + (size_t)c * 512 + lane * 8, &sB[(size_t)c * 512]);

    f32x4 acc[4], acc2[4];
#pragma unroll
    for (int nt = 0; nt < 4; ++nt) {
        acc[nt]  = (f32x4){0.f, 0.f, 0.f, 0.f};
        acc2[nt] = (f32x4){0.f, 0.f, 0.f, 0.f};
    }
    __syncthreads();

#pragma unroll
    for (int kk = 0; kk < KK; ++kk) {
#pragma unroll
        for (int nt = 0; nt < 4; ++nt) {
            const f16* bp = &sB[(size_t)((kk * 4 + nt) * 2) * 512] + lane * 8;
            const f16x8 bh = *(const f16x8*)bp;
            const f16x8 bl = *(const f16x8*)(bp + 512);
            acc[nt]  = __builtin_amdgcn_mfma_f32_16x16x32_f16(va[kk], bh, acc[nt], 0, 0, 0);
            acc2[nt] = __builtin_amdgcn_mfma_f32_16x16x32_f16(va[kk], bl, acc2[nt], 0, 0, 0);
            acc2[nt] = __builtin_amdgcn_mfma_f32_16x16x32_f16(vl[kk], bh, acc2[nt], 0, 0, 0);
        }
    }

    const int colg = lane & 15;
    const int rg   = lane >> 4;
#pragma unroll
    for (int nt = 0; nt < 4; ++nt) {
#pragma unroll
        for (int j = 0; j < 4; ++j) {
            const float r = acc[nt][j] + acc2[nt][j] * (1.f / 4096.f);
            const int n  = n0 + w * 16 + rg * 4 + j;
            const int co = nt * 16 + colg;
            if (n < N && co < 54)
                P[(size_t)(co >> 1) * N * 2 + (size_t)n * 2 + (co & 1)] = r;
        }
    }
}

// score(S) = sum_k P[k][nbr(S,k)]  (f32, k-ordered like the reference);
// also fills the coords columns of ppn.
__global__ __launch_bounds__(256)
void reduce_score(const float* __restrict__ P, const int* __restrict__ nbr,
                  const int* __restrict__ coords, float* __restrict__ ppn, int N)
{
    const int site = blockIdx.x * 256 + threadIdx.x;
    if (site >= N) return;
    float s0 = 0.f, s1 = 0.f;
    const size_t pl = (size_t)N * 2;
#pragma unroll
    for (int k = 0; k < 27; ++k) {
        const int idx = nbr[(size_t)site * 27 + k];
        if (idx >= 0) {
            const float2 p = *(const float2*)(P + (size_t)k * pl + (size_t)idx * 2);
            s0 += p.x; s1 += p.y;
        }
    }
    float* row = ppn + (size_t)site * 6;
    const int* cr = coords + (size_t)site * 4;
    row[0] = (float)cr[0]; row[1] = (float)cr[1];
    row[2] = (float)cr[2]; row[3] = (float)cr[3];
    row[4] = s0; row[5] = s1;
}

// ---------------------------------------------------------------------------
// Pre-pass: f32 rows (optionally x att-mask) -> f16 split planes, plus a
// zero row at index N (gather target for missing neighbors / tail sites).
// ---------------------------------------------------------------------------
template<int TERMS>
__global__ __launch_bounds__(256)
void prepass(const float* __restrict__ f, const float* __restrict__ att,
             f16* __restrict__ dst, size_t plane, int C4, int N)
{
    const size_t i = (size_t)blockIdx.x * 256 + threadIdx.x;
    const size_t total = (size_t)(N + 1) * C4;
    if (i >= total) return;
    const int row = (int)(i / C4);
    float4 v = make_float4(0.f, 0.f, 0.f, 0.f);
    if (row < N) {
        v = *(const float4*)(f + i * 4);
        if (att != nullptr) {
            const float a = att[row];
            v.x *= a; v.y *= a; v.z *= a; v.w *= a;
        }
    }
    const float xs[4] = {v.x, v.y, v.z, v.w};
    f16x4 hi, lo;
#pragma unroll
    for (int j = 0; j < 4; ++j) {
        const f16 h = (f16)xs[j];
        hi[j] = h;
        lo[j] = (f16)((xs[j] - (float)h) * 4096.f);
    }
    *(f16x4*)(dst + i * 4) = hi;
    if constexpr (TERMS == 2)
        *(f16x4*)(dst + plane + i * 4) = lo;
}

// Pack fp32 W[27][C][CO_real] into fragment chunks:
// chunk id = ((((k*CS + cs)*KK + kk)*NTB + nt)*TERMS + term), 512 f16 each.
__global__ __launch_bounds__(256)
void pack_w_f16(const float* __restrict__ W, f16* __restrict__ Wb,
                int C, int CO_real, int CS, int NTB, int TERMS)
{
    const int KK = C / 32;
    const int total = 27 * CS * KK * NTB * TERMS * 64;
    const int t = blockIdx.x * blockDim.x + threadIdx.x;
    if (t >= total) return;
    const int lane = t & 63;
    int cid = t >> 6;
    const int term = cid % TERMS; cid /= TERMS;
    const int nt   = cid % NTB;   cid /= NTB;
    const int kk   = cid % KK;    cid /= KK;
    const int cs   = cid % CS;
    const int k    = cid / CS;
    const int co   = (cs * NTB + nt) * 16 + (lane & 15);
#pragma unroll
    for (int j = 0; j < 8; ++j) {
        const int ci = kk * 32 + (lane >> 4) * 8 + j;
        const float x = (co < CO_real) ? W[((size_t)k * C + ci) * CO_real + co] : 0.f;
        const f16 h = (f16)x;
        Wb[(size_t)t * 8 + j] = (term == 0) ? h : (f16)((x - (float)h) * 4096.f);
    }
}

// Pack score weights [27][C][2] as a flat [C x 54->64] fragment set,
// chunk id = ((kk*4 + nt)*2 + term); flat col co = 2k + c.
__global__ __launch_bounds__(256)
void pack_ws_flat(const float* __restrict__ W, f16* __restrict__ Wb, int C)
{
    const int KK = C / 32;
    const int total = KK * 4 * 2 * 64;
    const int t = blockIdx.x * blockDim.x + threadIdx.x;
    if (t >= total) return;
    const int lane = t & 63;
    int cid = t >> 6;
    const int term = cid % 2;
    const int nt   = (cid >> 1) % 4;
    const int kk   = cid >> 3;
    const int co   = nt * 16 + (lane & 15);
#pragma unroll
    for (int j = 0; j < 8; ++j) {
        const int ci = kk * 32 + (lane >> 4) * 8 + j;
        const float x = (co < 54) ? W[((size_t)(co >> 1) * C + ci) * 2 + (co & 1)] : 0.f;
        const f16 h = (f16)x;
        Wb[(size_t)t * 8 + j] = (term == 0) ? h : (f16)((x - (float)h) * 4096.f);
    }
}

// Pack the fused head [27][32][{3|2|5}->10] directly into fragment chunks
// (chunk per k; single term).
__global__ __launch_bounds__(256)
void pack_wh_frag(const float* __restrict__ wp, const float* __restrict__ ws,
                  const float* __restrict__ wt, f16* __restrict__ Wb)
{
    const int t = blockIdx.x * blockDim.x + threadIdx.x;
    if (t >= 27 * 64) return;
    const int lane = t & 63;
    const int k    = t >> 6;
    const int co   = lane & 15;
#pragma unroll
    for (int j = 0; j < 8; ++j) {
        const int ci = (lane >> 4) * 8 + j;
        float x = 0.f;
        if (co < 3)       x = wp[((size_t)k * 32 + ci) * 3 + co];
        else if (co < 5)  x = ws[((size_t)k * 32 + ci) * 2 + (co - 3)];
        else if (co < 10) x = wt[((size_t)k * 32 + ci) * 5 + (co - 5)];
        Wb[(size_t)t * 8 + j] = (f16)x;
    }
}

__global__ __launch_bounds__(256)
void att_kernel(const float* __restrict__ ppn, const int* __restrict__ parent,
                float* __restrict__ att, int N)
{
    const int i = blockIdx.x * blockDim.x + threadIdx.x;
    if (i >= N) return;
    const int p = parent[i];
    const float s0 = ppn[(size_t)p * 6 + 4];
    const float s1 = ppn[(size_t)p * 6 + 5];
    const float m  = fmaxf(s0, s1);
    const float e0 = expf(s0 - m);
    const float e1 = expf(s1 - m);
    const float p1 = e1 / (e0 + e1);
    att[i] = (p1 > 0.8f) ? 1.f : 0.f;
}

extern "C" void kernel_launch(void* const* d_in, const int* in_sizes, int n_in,
                              void* d_out, int out_size, void* d_ws, size_t ws_size,
                              hipStream_t stream)
{
    const float* f1       = (const float*)d_in[0];
    const float* f2       = (const float*)d_in[1];
    const float* f3       = (const float*)d_in[2];
    const float* w1_conv  = (const float*)d_in[3];
    const float* w1_score = (const float*)d_in[4];
    const float* w2_conv  = (const float*)d_in[5];
    const float* w2_score = (const float*)d_in[6];
    const float* w3_conv  = (const float*)d_in[7];
    const float* w3_pix   = (const float*)d_in[8];
    const float* w3_score = (const float*)d_in[9];
    const float* w3_type  = (const float*)d_in[10];
    const int* coords1    = (const int*)d_in[11];
    const int* coords2    = (const int*)d_in[12];
    const int* nbr1       = (const int*)d_in[13];
    const int* nbr2       = (const int*)d_in[14];
    const int* nbr3       = (const int*)d_in[15];
    const int* parent12   = (const int*)d_in[16];
    const int* parent23   = (const int*)d_in[17];

    const int N1 = in_sizes[0] / 160;   // 20000
    const int N2 = in_sizes[1] / 96;    // 160000
    const int N3 = in_sizes[2] / 32;    // 320000

    // Output layout: points[N3,10] | ppn1[N1,6] | ppn2[N2,6] | att[N2] | att2[N3]
    float* points = (float*)d_out;
    float* ppn1   = points + (size_t)N3 * 10;
    float* ppn2   = ppn1 + (size_t)N1 * 6;
    float* attn   = ppn2 + (size_t)N2 * 6;
    float* attn2  = attn + (size_t)N2;

    // Workspace (all conv inputs have N+1 rows; row N = zeros).
    // Region reuse by lifetime:
    //   f1s region: f1 split (conv1) -> P1 (pgemm1/reduce1) -> f3s (level 3)
    //   f2s region: f2 split (conv2) -> P2 (pgemm2/reduce2) -> zs (conv3/head)
    const size_t p1 = (size_t)(N1 + 1) * 160;
    const size_t p2 = (size_t)(N2 + 1) * 96;
    f16* f1s  = (f16*)d_ws;           // 2*p1
    f16* xs   = f1s + 2 * p1;         // 2*p1
    f16* f2s  = xs + 2 * p1;          // 2*p2
    f16* ys   = f2s + 2 * p2;         // 2*p2
    float* P1 = (float*)f1s;          // 27*N1*2 f32 (4.3MB <= 12.8MB)
    f16* f3s  = f1s;                  // (N3+1)*32 f16 (20.5MB <= 25.6MB w/ xs)
    float* P2 = (float*)f2s;          // 27*N2*2 f32 (34.6MB <= 61.4MB)
    f16* zs   = f2s;                  // (N3+1)*32 f16 (after P2 dead)
    f16* Wb1  = ys + 2 * p2;          // 2700 chunks
    f16* Wb2  = Wb1 + (size_t)2700 * 512;   // 972
    f16* Wb3  = Wb2 + (size_t)972 * 512;    // 54
    f16* Wbh  = Wb3 + (size_t)54 * 512;     // 27
    f16* Wsf1 = Wbh + (size_t)27 * 512;     // 40 (score1 flat)
    f16* Wsf2 = Wsf1 + (size_t)40 * 512;    // 24 (score2 flat)

    // ---- weight packing ----
    pack_w_f16<<<(2700 * 64 + 255) / 256, 256, 0, stream>>>(w1_conv, Wb1, 160, 160, 5, 2, 2);
    pack_w_f16<<<(972 * 64 + 255) / 256, 256, 0, stream>>>(w2_conv, Wb2, 96, 96, 2, 3, 2);
    pack_w_f16<<<(54 * 64 + 255) / 256, 256, 0, stream>>>(w3_conv, Wb3, 32, 32, 1, 2, 1);
    pack_wh_frag<<<(27 * 64 + 255) / 256, 256, 0, stream>>>(w3_pix, w3_score, w3_type, Wbh);
    pack_ws_flat<<<(40 * 64 + 255) / 256, 256, 0, stream>>>(w1_score, Wsf1, 160);
    pack_ws_flat<<<(24 * 64 + 255) / 256, 256, 0, stream>>>(w2_score, Wsf2, 96);

    // ---- level 1 ----
    prepass<2><<<(int)(((size_t)(N1 + 1) * 40 + 255) / 256), 256, 0, stream>>>(
        f1, nullptr, f1s, p1, 40, N1);
    // conv1: C=160 NTB=2 CS=5, 8 waves, dbuf, reorder (no PIPEA: KK=5 VGPR).
    // tiles=157 -> pad 160 (nwg=800 %8==0).
    conv_mfma<160, 2, 5, 2, 8, 1, 2, 0><<<160 * 5, 512, 0, stream>>>(
        f1s, p1, nbr1, Wb1, xs, 160, 0, p1, 160, N1, N1 + 1, 160);
    pgemm_score<160><<<(N1 + 63) / 64, 256, 0, stream>>>(xs, p1, Wsf1, P1, N1);
    reduce_score<<<(N1 + 255) / 256, 256, 0, stream>>>(P1, nbr1, coords1, ppn1, N1);
    att_kernel<<<(N2 + 255) / 256, 256, 0, stream>>>(ppn1, parent12, attn, N2);

    // ---- level 2 ----
    prepass<2><<<(int)(((size_t)(N2 + 1) * 24 + 255) / 256), 256, 0, stream>>>(
        f2, attn, f2s, p2, 24, N2);
    // conv2: C=96 NTB=3 CS=2, 8 waves, dbuf, PIPEA. tiles=1251 -> pad 1252
    // (nwg=2504 %8==0).
    conv_mfma<96, 3, 2, 2, 8, 1, 2, 1><<<1252 * 2, 512, 0, stream>>>(
        f2s, p2, nbr2, Wb2, ys, 96, 0, p2, 96, N2, N2 + 1, 1252);
    pgemm_score<96><<<(N2 + 63) / 64, 256, 0, stream>>>(ys, p2, Wsf2, P2, N2);
    reduce_score<<<(N2 + 255) / 256, 256, 0, stream>>>(P2, nbr2, coords2, ppn2, N2);
    att_kernel<<<(N3 + 255) / 256, 256, 0, stream>>>(ppn2, parent23, attn2, N3);

    // ---- level 3 (points chain, single-term f16) ----
    prepass<1><<<(int)(((size_t)(N3 + 1) * 8 + 255) / 256), 256, 0, stream>>>(
        f3, attn2, f3s, 0, 8, N3);
    // conv3: C=32 NTB=2 whole-B (54KB), no k-loop barriers, PIPEA.
    // tiles=2501 -> pad 2504.
    conv_mfma<32, 2, 1, 1, 8, 0, 1, 1><<<2504, 512, 0, stream>>>(
        f3s, 0, nbr3, Wb3, zs, 32, 0, 0, 32, N3, N3 + 1, 2504);
    // head: C=32 NTB=1 whole-B (27KB), PIPEA. tiles=2500 -> pad 2504.
    conv_mfma<32, 1, 1, 1, 8, 0, 0, 1><<<2504, 512, 0, stream>>>(
        zs, 0, nbr3, Wbh, points, 10, 0, 0, 10, N3, N3, 2504);
}